// Round 20
// baseline (809.437 us; speedup 1.0000x reference)
//
#include <hip/hip_runtime.h>
#include <hip/hip_bf16.h>

#define NN 16384      // nodes
#define NE 262144     // edges
#define HIDD 1024
#define DD 768
#define RR 6
#define BB 4
#define LL 2
#define BN_EPS 1e-5f
#define LN_EPS 1e-5f

typedef __attribute__((ext_vector_type(8))) short bf16x8;
typedef __attribute__((ext_vector_type(4))) float f32x4;

__device__ __forceinline__ float b2f(unsigned short u) {
  union { unsigned int i; float f; } c;
  c.i = ((unsigned int)u) << 16;
  return c.f;
}
__device__ __forceinline__ unsigned short f2b(float f) {  // RNE
  union { float f; unsigned int u; } c;
  c.f = f;
  unsigned int x = c.u;
  x += 0x7FFFu + ((x >> 16) & 1u);
  return (unsigned short)(x >> 16);
}

__device__ __forceinline__ void gll16(const unsigned short* g, unsigned short* l) {
  __builtin_amdgcn_global_load_lds(
      (const __attribute__((address_space(1))) unsigned int*)g,
      (__attribute__((address_space(3))) unsigned int*)l, 16, 0, 0);
}

// dtype detector: flag=1 -> inputs f32, flag=0 -> inputs bf16.
__global__ void k_detect(const unsigned short* __restrict__ h, int* __restrict__ flag) {
  __shared__ int sh[256];
  int cnt = 0;
  for (int k = 0; k < 256; ++k) {
    ushort4 t = *(const ushort4*)&h[(size_t)(k * 256 + threadIdx.x) * 4];
    if ((t.x & 0x7F80) == 0x7F80) cnt++;
    if ((t.y & 0x7F80) == 0x7F80) cnt++;
    if ((t.z & 0x7F80) == 0x7F80) cnt++;
    if ((t.w & 0x7F80) == 0x7F80) cnt++;
  }
  sh[threadIdx.x] = cnt;
  __syncthreads();
  if (threadIdx.x == 0) {
    int t = 0;
    for (int i = 0; i < 256; ++i) t += sh[i];
    flag[0] = (t > 16) ? 1 : 0;
  }
}

// MODE: 0 = raw input (flag-dependent), 1 = f32, 2 = bf16
template <int MODE>
__device__ __forceinline__ float load1t(const void* p, size_t i, int isf32) {
  if (MODE == 1 || (MODE == 0 && isf32)) return ((const float*)p)[i];
  return b2f(((const unsigned short*)p)[i]);
}

// batched param conversion: 8 segments -> fpar
__global__ void k_cvt8(const void* s0, const void* s1, const void* s2, const void* s3,
                       const void* s4, const void* s5, const void* s6, const void* s7,
                       float* __restrict__ fpar, const int* __restrict__ flagp) {
  const int isf32 = flagp[0];
  const int seg = blockIdx.y;
  const int lens[8] = {768, 48, 1536, 1536, 1536, 1024, 1024, 1024};
  const int offs_[8] = {0, 768, 816, 2352, 3888, 5424, 6448, 7472};
  const void* srcs[8] = {s0, s1, s2, s3, s4, s5, s6, s7};
  int i = blockIdx.x * 256 + threadIdx.x;
  if (i < lens[seg]) fpar[offs_[seg] + i] = load1t<0>(srcs[seg], i, isf32);
}

// raw input -> bf16 copy
__global__ void k_cvtb(const void* __restrict__ in, unsigned short* __restrict__ out,
                       int n, const int* __restrict__ flagp) {
  const int isf32 = flagp[0];
  int i = blockIdx.x * 256 + threadIdx.x;
  if (i < n) out[i] = f2b(load1t<0>(in, (size_t)i, isf32));
}

// diagnostic fill (f32 out)
__global__ void k_fill(float* __restrict__ out, long n, float val) {
  long i = (long)blockIdx.x * 256 + threadIdx.x;
  if (i < n) out[i] = val;
}

// LDS-tiled transpose: src [I][J] -> dst[j*dstStride + dstOff + i] bf16.
// Optional per-row scale (rowsc[i]) applied at load; rowsc==nullptr -> 1.
__global__ __launch_bounds__(256) void k_transpose(const void* __restrict__ src,
                                                   long ioff,
                                                   unsigned short* __restrict__ dst,
                                                   int I, int J, int dstStride,
                                                   int dstOff,
                                                   const float* __restrict__ rowsc,
                                                   const int* __restrict__ flagp) {
  const int isf32 = flagp[0];
  __shared__ unsigned short t[64][65];
  const int j0 = blockIdx.x * 64, i0 = blockIdx.y * 64;
  const int tx = threadIdx.x & 63, ty = threadIdx.x >> 6;
  for (int rr = ty; rr < 64; rr += 4) {
    float sc = rowsc ? rowsc[i0 + rr] : 1.0f;
    t[rr][tx] = f2b(sc * load1t<0>(src, (size_t)ioff + (size_t)(i0 + rr) * J + j0 + tx, isf32));
  }
  __syncthreads();
  for (int rr = ty; rr < 64; rr += 4)
    dst[(size_t)(j0 + rr) * dstStride + dstOff + i0 + tx] = t[tx][rr];
}

// batched: BTcat[n][z*768 + k] = W_z[k][n]; z=0 root (rows scaled by grho[k]),
// z=1..4 basis[z-1] (unscaled)
__global__ __launch_bounds__(256) void k_tbatch(const void* __restrict__ root, long roff,
                                                const void* __restrict__ basis, long boff,
                                                const float* __restrict__ grho,
                                                unsigned short* __restrict__ BT,
                                                const int* __restrict__ flagp) {
  const int isf32 = flagp[0];
  const int z = blockIdx.z;
  const void* src = (z == 0) ? root : basis;
  const long off = (z == 0) ? roff : boff + (long)(z - 1) * DD * DD;
  __shared__ unsigned short t[64][65];
  const int j0 = blockIdx.x * 64, i0 = blockIdx.y * 64;
  const int tx = threadIdx.x & 63, ty = threadIdx.x >> 6;
  for (int rr = ty; rr < 64; rr += 4) {
    float sc = (z == 0) ? grho[i0 + rr] : 1.0f;
    t[rr][tx] = f2b(sc * load1t<0>(src, (size_t)off + (size_t)(i0 + rr) * DD + j0 + tx, isf32));
  }
  __syncthreads();
  for (int rr = ty; rr < 64; rr += 4)
    BT[(size_t)(j0 + rr) * (5 * DD) + z * DD + i0 + tx] = t[tx][rr];
}

// affine init: grho=1, dlt=0; zero rbias + stats. grid 8x256.
__global__ void k_affinit(float* __restrict__ grho, float* __restrict__ dlt,
                          float* __restrict__ rbias, float* __restrict__ stats) {
  int i = blockIdx.x * 256 + threadIdx.x;
  if (i < DD) { grho[i] = 1.0f; dlt[i] = 0.0f; rbias[i] = 0.0f; }
  if (i < 2 * DD) stats[i] = 0.0f;
}

// affine from BN stats; also re-zero stats and zero zbuf[0..zn). grid 4x256.
__global__ void k_aff(float* __restrict__ sums, float* __restrict__ sqs,
                      const float* __restrict__ gamma, const float* __restrict__ beta,
                      float* __restrict__ grho, float* __restrict__ dlt,
                      float* __restrict__ zbuf, int zn) {
  int c = blockIdx.x * 256 + threadIdx.x;
  if (c < DD) {
    float mu = sums[c] * (1.0f / NN);
    float var = sqs[c] * (1.0f / NN) - mu * mu;
    float gr = gamma[c] * rsqrtf(var + BN_EPS);
    grho[c] = gr;
    dlt[c] = beta[c] - gr * mu;
    sums[c] = 0.0f;
    sqs[c] = 0.0f;
  }
  if (c < zn) zbuf[c] = 0.0f;
}

// outb[n] += base[n](chunk0) + sum_{k in chunk} delta[k]*mat[ioff+k*J+n]
// grid = (J/256, 16 k-chunks of 48). outb must be zeroed.
__global__ void k_rowbias(const void* __restrict__ mat, long ioff, int J,
                          const float* __restrict__ delta,
                          const float* __restrict__ base,
                          float* __restrict__ outb,
                          const int* __restrict__ flagp) {
  const int isf32 = flagp[0];
  const int n = blockIdx.x * 256 + threadIdx.x;
  if (n >= J) return;
  const int kc = blockIdx.y;
  float s = (kc == 0 && base) ? base[n] : 0.0f;
  const int k0 = kc * 48;
#pragma unroll 4
  for (int k = k0; k < k0 + 48; ++k)
    s += delta[k] * load1t<0>(mat, (size_t)ioff + (size_t)k * J + n, isf32);
  atomicAdd(&outb[n], s);
}

// ---------------------------------------------------------------------------
// MFMA bf16 GEMM: C[M,N] = A[M,K] @ Bt[N,K]^T (+bias)(relu)
// 128x128 tile, 4 waves, BK=64, 16x16x32 MFMA, gll16 staging, XOR bank
// permutation, bijective XCD swizzle. R16/R19-proven structure.
// ---------------------------------------------------------------------------
template <int BIAS, int RELU, int OUTB>
__global__ __launch_bounds__(256) void k_mgemm(const unsigned short* __restrict__ A,
                                               const unsigned short* __restrict__ Bt,
                                               const float* __restrict__ bias,
                                               void* __restrict__ C,
                                               int M, int Nn, int K) {
  __shared__ __align__(16) unsigned short Alds[2][128 * 32];
  __shared__ __align__(16) unsigned short Blds[2][128 * 32];
  const int tid = threadIdx.x;
  const int lane = tid & 63, w = tid >> 6;
  const int wm = w >> 1, wn = w & 1;
  const int fr = lane & 15, kg = lane >> 4;
  const int nwg = gridDim.x;
  int id = blockIdx.x;
  if ((nwg & 7) == 0) id = (id & 7) * (nwg >> 3) + (id >> 3);
  const int gx = Nn >> 7;
  const int m0 = (id / gx) * 128, n0 = (id % gx) * 128;

  const int srow = w * 16 + (lane >> 2);
  const int sslot = (lane & 3) ^ ((lane >> 3) & 3);
  const unsigned short* ga = A + (size_t)(m0 + srow) * K + sslot * 8;
  const unsigned short* ga2 = ga + (size_t)64 * K;
  const unsigned short* gb = Bt + (size_t)(n0 + srow) * K + sslot * 8;
  const unsigned short* gb2 = gb + (size_t)64 * K;
  const int wo = w * 512;
  const int roff = fr * 32 + ((kg ^ ((fr >> 1) & 3)) * 8);

  f32x4 acc[4][4] = {};

  for (int k0 = 0; k0 < K; k0 += 64) {
    gll16(ga + k0, &Alds[0][wo]);
    gll16(ga2 + k0, &Alds[0][wo + 2048]);
    gll16(gb + k0, &Blds[0][wo]);
    gll16(gb2 + k0, &Blds[0][wo + 2048]);
    gll16(ga + k0 + 32, &Alds[1][wo]);
    gll16(ga2 + k0 + 32, &Alds[1][wo + 2048]);
    gll16(gb + k0 + 32, &Blds[1][wo]);
    gll16(gb2 + k0 + 32, &Blds[1][wo + 2048]);
    __syncthreads();
#pragma unroll
    for (int kh = 0; kh < 2; ++kh) {
      bf16x8 af[4], bfr[4];
#pragma unroll
      for (int i = 0; i < 4; ++i) {
        af[i] = *(const bf16x8*)(&Alds[kh][(wm * 4 + i) * 512 + roff]);
        bfr[i] = *(const bf16x8*)(&Blds[kh][(wn * 4 + i) * 512 + roff]);
      }
#pragma unroll
      for (int i = 0; i < 4; ++i)
#pragma unroll
        for (int j = 0; j < 4; ++j)
          acc[i][j] = __builtin_amdgcn_mfma_f32_16x16x32_bf16(af[i], bfr[j],
                                                              acc[i][j], 0, 0, 0);
    }
    __syncthreads();
  }

  const int orow = (lane >> 4) * 4;
#pragma unroll
  for (int i = 0; i < 4; ++i) {
#pragma unroll
    for (int j = 0; j < 4; ++j) {
      const int n = n0 + wn * 64 + j * 16 + fr;
      const float bv = BIAS ? bias[n] : 0.f;
#pragma unroll
      for (int rg = 0; rg < 4; ++rg) {
        const int m = m0 + wm * 64 + i * 16 + orow + rg;
        const size_t off = (size_t)m * Nn + n;
        float v = acc[i][j][rg] + bv;
        if (RELU) v = fmaxf(v, 0.f);
        if (OUTB) ((unsigned short*)C)[off] = f2b(v);
        else      ((float*)C)[off] = v;
      }
    }
  }
}

// ---------------------------------------------------------------------------
// Fused layer GEMM + epilogue (BN folded), BM=128 x BN=192 tile:
// wave tile 64x96 -> 24 MFMA per K32 sub-chunk per wave (1.5x the 128^2
// shape) against the same barrier drain. BK=64 (2x32 sub-chunks), drained
// barriers (R16-proven sync). grid = 512 (4 n-tiles x 128 m-tiles).
//   acc = [ybprev|Y01|Y23] @ BTcat^T; v = relu(acc+rbias) + affine(ybprev)
//   ybnew = bf16(v); column stats via LDS + global atomics.
// ---------------------------------------------------------------------------
__global__ __launch_bounds__(256) void k_mgemm3(const unsigned short* __restrict__ ybprev,
                                                const unsigned short* __restrict__ Y01,
                                                const unsigned short* __restrict__ Y23,
                                                const unsigned short* __restrict__ BT,
                                                const float* __restrict__ rbias,
                                                const float* __restrict__ grho,
                                                const float* __restrict__ dlt,
                                                unsigned short* __restrict__ ybnew,
                                                float* __restrict__ sums,
                                                float* __restrict__ sqs) {
  __shared__ __align__(16) unsigned short Alds[2][128 * 32];   // 8 KB each
  __shared__ __align__(16) unsigned short Blds[2][192 * 32];   // 12 KB each
  __shared__ float csum[192], csq[192];
  const int tid = threadIdx.x;
  const int lane = tid & 63, w = tid >> 6;
  const int wm = w >> 1, wn = w & 1;
  const int fr = lane & 15, kg = lane >> 4;
  const int nwg = gridDim.x;        // 512
  int id = blockIdx.x;
  id = (id & 7) * (nwg >> 3) + (id >> 3);
  const int m0 = (id / 4) * 128, n0 = (id % 4) * 192;

  const int srow = w * 16 + (lane >> 2);
  const int sslot = (lane & 3) ^ ((lane >> 3) & 3);
  const unsigned short* gxp = ybprev + (size_t)(m0 + srow) * DD + sslot * 8;
  const unsigned short* gxp2 = gxp + (size_t)64 * DD;
  const unsigned short* gy = Y01 + (size_t)(m0 + srow) * 1536 + sslot * 8;
  const unsigned short* gy2 = gy + (size_t)64 * 1536;
  const unsigned short* gz = Y23 + (size_t)(m0 + srow) * 1536 + sslot * 8;
  const unsigned short* gz2 = gz + (size_t)64 * 1536;
  // B: 192 rows in 3 passes of 64
  const unsigned short* gb0 = BT + (size_t)(n0 + srow) * 3840 + sslot * 8;
  const unsigned short* gb1 = gb0 + (size_t)64 * 3840;
  const unsigned short* gb2 = gb0 + (size_t)128 * 3840;
  const int wo = w * 512;
  const int roff = fr * 32 + ((kg ^ ((fr >> 1) & 3)) * 8);

  f32x4 acc[4][6] = {};

  for (int k0 = 0; k0 < 3840; k0 += 64) {
    const unsigned short *pa, *pa2;
    long ko;
    if (k0 < 768)       { pa = gxp; pa2 = gxp2; ko = k0; }
    else if (k0 < 2304) { pa = gy;  pa2 = gy2;  ko = k0 - 768; }
    else                { pa = gz;  pa2 = gz2;  ko = k0 - 2304; }
#pragma unroll
    for (int s = 0; s < 2; ++s) {
      gll16(pa + ko + 32 * s, &Alds[s][wo]);
      gll16(pa2 + ko + 32 * s, &Alds[s][wo + 2048]);
      gll16(gb0 + k0 + 32 * s, &Blds[s][wo]);
      gll16(gb1 + k0 + 32 * s, &Blds[s][wo + 2048]);
      gll16(gb2 + k0 + 32 * s, &Blds[s][wo + 4096]);
    }
    __syncthreads();
#pragma unroll
    for (int kh = 0; kh < 2; ++kh) {
      bf16x8 af[4], bfr[6];
#pragma unroll
      for (int i = 0; i < 4; ++i)
        af[i] = *(const bf16x8*)(&Alds[kh][(wm * 4 + i) * 512 + roff]);
#pragma unroll
      for (int j = 0; j < 6; ++j)
        bfr[j] = *(const bf16x8*)(&Blds[kh][(wn * 6 + j) * 512 + roff]);
#pragma unroll
      for (int i = 0; i < 4; ++i)
#pragma unroll
        for (int j = 0; j < 6; ++j)
          acc[i][j] = __builtin_amdgcn_mfma_f32_16x16x32_bf16(af[i], bfr[j],
                                                              acc[i][j], 0, 0, 0);
    }
    __syncthreads();
  }

  if (tid < 192) { csum[tid] = 0.f; csq[tid] = 0.f; }
  __syncthreads();
  const int orow = (lane >> 4) * 4;
#pragma unroll
  for (int j = 0; j < 6; ++j) {
    const int nloc = wn * 96 + j * 16 + fr;
    const int n = n0 + nloc;
    const float rb = rbias[n];
    const float gr = grho[n], dl = dlt[n];
    float ps = 0.f, pq = 0.f;
#pragma unroll
    for (int i = 0; i < 4; ++i) {
#pragma unroll
      for (int rg = 0; rg < 4; ++rg) {
        const int m = m0 + wm * 64 + i * 16 + orow + rg;
        float xin = gr * b2f(ybprev[(size_t)m * DD + n]) + dl;
        float v = fmaxf(acc[i][j][rg] + rb, 0.f) + xin;
        ybnew[(size_t)m * DD + n] = f2b(v);
        ps += v;
        pq += v * v;
      }
    }
    atomicAdd(&csum[nloc], ps);
    atomicAdd(&csq[nloc], pq);
  }
  __syncthreads();
  if (tid < 192) {
    atomicAdd(&sums[n0 + tid], csum[tid]);
    atomicAdd(&sqs[n0 + tid], csq[tid]);
  }
}

// counts[r,dst] += 1
__global__ void k_count(const int* __restrict__ et, const int* __restrict__ dst,
                        float* __restrict__ counts) {
  int e = blockIdx.x * 256 + threadIdx.x;
  if (e < NE) atomicAdd(&counts[(size_t)et[e] * NN + dst[e]], 1.0f);
}

// ---- CSR build (by dst) -----------------------------------------------------
__global__ void k_deg(const int* __restrict__ dst, int* __restrict__ deg) {
  int e = blockIdx.x * 256 + threadIdx.x;
  if (e < NE) atomicAdd(&deg[dst[e]], 1);
}

__global__ __launch_bounds__(256) void k_scan(const int* __restrict__ deg,
                                              int* __restrict__ offs,
                                              int* __restrict__ cursor) {
  __shared__ int part[256];
  const int base = threadIdx.x * 64;
  int s = 0;
  for (int i = 0; i < 64; ++i) s += deg[base + i];
  part[threadIdx.x] = s;
  __syncthreads();
  if (threadIdx.x == 0) {
    int run = 0;
    for (int i = 0; i < 256; ++i) { int t = part[i]; part[i] = run; run += t; }
  }
  __syncthreads();
  int run = part[threadIdx.x];
  for (int i = 0; i < 64; ++i) {
    offs[base + i] = run;
    cursor[base + i] = run;
    run += deg[base + i];
  }
  if (threadIdx.x == 255) offs[NN] = run;
}

// elist[slot] = src | (et<<20)
__global__ void k_place(const int* __restrict__ src, const int* __restrict__ dst,
                        const int* __restrict__ et, int* __restrict__ cursor,
                        int* __restrict__ elist) {
  int e = blockIdx.x * 256 + threadIdx.x;
  if (e >= NE) return;
  int d = dst[e];
  int slot = atomicAdd(&cursor[d], 1);
  elist[slot] = src[e] | (et[e] << 20);
}

// ---- single-pass gather on raw yb, BN affine applied at write, 8-edge ILP
__global__ __launch_bounds__(192) void k_gather4(const int* __restrict__ offs,
                                                 const int* __restrict__ elist,
                                                 const float* __restrict__ counts,
                                                 const float* __restrict__ compL,
                                                 const float* __restrict__ grho,
                                                 const float* __restrict__ dlt,
                                                 const unsigned short* __restrict__ yb,
                                                 unsigned short* __restrict__ Y01,
                                                 unsigned short* __restrict__ Y23) {
  const int d = blockIdx.x;
  const int tid = threadIdx.x;
  __shared__ float sw[RR][4];
  if (tid < 4 * RR) {
    const int r = tid >> 2, j = tid & 3;
    const float c = counts[(size_t)r * NN + d];
    sw[r][j] = (c > 0.f) ? compL[r * BB + j] / c : 0.f;
  }
  __syncthreads();
  const int beg = offs[d], end = offs[d + 1];
  float a0[4] = {}, a1[4] = {}, a2[4] = {}, a3[4] = {};
  float ws0 = 0.f, ws1 = 0.f, ws2 = 0.f, ws3 = 0.f;
  int e = beg;
  for (; e + 7 < end; e += 8) {
    int v[8];
#pragma unroll
    for (int q = 0; q < 8; ++q) v[q] = elist[e + q];
    ushort4 t[8];
#pragma unroll
    for (int q = 0; q < 8; ++q)
      t[q] = *(const ushort4*)&yb[(size_t)(v[q] & 0xFFFFF) * DD + tid * 4];
#pragma unroll
    for (int q = 0; q < 8; ++q) {
      const int r = v[q] >> 20;
      const float w0 = sw[r][0], w1 = sw[r][1], w2 = sw[r][2], w3 = sw[r][3];
      ws0 += w0; ws1 += w1; ws2 += w2; ws3 += w3;
      const float f[4] = {b2f(t[q].x), b2f(t[q].y), b2f(t[q].z), b2f(t[q].w)};
#pragma unroll
      for (int c = 0; c < 4; ++c) {
        a0[c] += w0 * f[c];
        a1[c] += w1 * f[c];
        a2[c] += w2 * f[c];
        a3[c] += w3 * f[c];
      }
    }
  }
  for (; e < end; ++e) {
    const int v = elist[e];
    const int s = v & 0xFFFFF, r = v >> 20;
    ushort4 t = *(const ushort4*)&yb[(size_t)s * DD + tid * 4];
    const float w0 = sw[r][0], w1 = sw[r][1], w2 = sw[r][2], w3 = sw[r][3];
    ws0 += w0; ws1 += w1; ws2 += w2; ws3 += w3;
    const float f[4] = {b2f(t.x), b2f(t.y), b2f(t.z), b2f(t.w)};
#pragma unroll
    for (int c = 0; c < 4; ++c) {
      a0[c] += w0 * f[c];
      a1[c] += w1 * f[c];
      a2[c] += w2 * f[c];
      a3[c] += w3 * f[c];
    }
  }
  const float4 gr = *(const float4*)&grho[tid * 4];
  const float4 dl = *(const float4*)&dlt[tid * 4];
  const float grv[4] = {gr.x, gr.y, gr.z, gr.w};
  const float dlv[4] = {dl.x, dl.y, dl.z, dl.w};
  ushort4 o;
  o.x = f2b(grv[0] * a0[0] + dlv[0] * ws0);
  o.y = f2b(grv[1] * a0[1] + dlv[1] * ws0);
  o.z = f2b(grv[2] * a0[2] + dlv[2] * ws0);
  o.w = f2b(grv[3] * a0[3] + dlv[3] * ws0);
  *(ushort4*)&Y01[(size_t)d * 1536 + tid * 4] = o;
  o.x = f2b(grv[0] * a1[0] + dlv[0] * ws1);
  o.y = f2b(grv[1] * a1[1] + dlv[1] * ws1);
  o.z = f2b(grv[2] * a1[2] + dlv[2] * ws1);
  o.w = f2b(grv[3] * a1[3] + dlv[3] * ws1);
  *(ushort4*)&Y01[(size_t)d * 1536 + DD + tid * 4] = o;
  o.x = f2b(grv[0] * a2[0] + dlv[0] * ws2);
  o.y = f2b(grv[1] * a2[1] + dlv[1] * ws2);
  o.z = f2b(grv[2] * a2[2] + dlv[2] * ws2);
  o.w = f2b(grv[3] * a2[3] + dlv[3] * ws2);
  *(ushort4*)&Y23[(size_t)d * 1536 + tid * 4] = o;
  o.x = f2b(grv[0] * a3[0] + dlv[0] * ws3);
  o.y = f2b(grv[1] * a3[1] + dlv[1] * ws3);
  o.z = f2b(grv[2] * a3[2] + dlv[2] * ws3);
  o.w = f2b(grv[3] * a3[3] + dlv[3] * ws3);
  *(ushort4*)&Y23[(size_t)d * 1536 + DD + tid * 4] = o;
}

// row LayerNorm over HID=1024, f32 in/out, in-place safe
__global__ __launch_bounds__(256) void k_layernorm(const float* __restrict__ hf,
                                                   const float* __restrict__ gamma,
                                                   const float* __restrict__ beta,
                                                   float* __restrict__ out) {
  const int row = blockIdx.x;
  const float* h = hf + (size_t)row * HIDD;
  float v[4];
  float s = 0.f, sq = 0.f;
#pragma unroll
  for (int j = 0; j < 4; ++j) {
    v[j] = h[threadIdx.x + j * 256];
    s += v[j];
    sq += v[j] * v[j];
  }
#pragma unroll
  for (int off = 32; off > 0; off >>= 1) {
    s += __shfl_down(s, off);
    sq += __shfl_down(sq, off);
  }
  __shared__ float ps[4], pq[4];
  const int lane = threadIdx.x & 63, wv = threadIdx.x >> 6;
  if (lane == 0) { ps[wv] = s; pq[wv] = sq; }
  __syncthreads();
  if (threadIdx.x == 0) {
    float ts = ps[0] + ps[1] + ps[2] + ps[3];
    float tq = pq[0] + pq[1] + pq[2] + pq[3];
    float mu = ts * (1.0f / HIDD);
    float var = tq * (1.0f / HIDD) - mu * mu;
    ps[0] = mu;
    pq[0] = rsqrtf(var + LN_EPS);
  }
  __syncthreads();
  const float mu = ps[0], rstd = pq[0];
#pragma unroll
  for (int j = 0; j < 4; ++j) {
    const int c = threadIdx.x + j * 256;
    out[(size_t)row * HIDD + c] = gamma[c] * (v[j] - mu) * rstd + beta[c];
  }
}

extern "C" void kernel_launch(void* const* d_in, const int* in_sizes, int n_in,
                              void* d_out, int out_size, void* d_ws, size_t ws_size,
                              hipStream_t stream) {
  const void* h_text = d_in[0];
  const int* ei      = (const int*)d_in[1];
  const int* etype   = (const int*)d_in[2];
  const void* w_in  = d_in[3];
  const void* b_in  = d_in[4];
  const void* basis = d_in[5];
  const void* comp  = d_in[6];
  const void* root  = d_in[7];
  const void* convb = d_in[8];
  const void* bn_g  = d_in[9];
  const void* bn_b  = d_in[10];
  const void* w_out = d_in[11];
  const void* b_out = d_in[12];
  const void* ln_g  = d_in[13];
  const void* ln_b  = d_in[14];
  float* out = (float*)d_out;      // output is f32

  const int* src = ei;
  const int* dst = ei + NE;

  // ---- ws layout (byte offsets, 64B-aligned). Total ~108.3 MB.
  char* W = (char*)d_ws;
  int*   flags  = (int*)(W + 0);              // 256 B
  float* stats  = (float*)(W + 256);          // 6144 B
  float* fpar   = (float*)(W + 6400);         // 33984 B
  float* f_bin  = fpar;
  float* f_comp = fpar + 768;
  float* f_cb   = fpar + 816;
  float* f_bng  = fpar + 2352;
  float* f_bnb  = fpar + 3888;
  float* f_bout = fpar + 5424;
  float* f_lng  = fpar + 6448;
  float* f_lnb  = fpar + 7472;
  float* affA_g = (float*)(W + 40384);
  float* affA_d = affA_g + DD;
  float* affB_g = (float*)(W + 46528);
  float* affB_d = affB_g + DD;
  float* rbias  = (float*)(W + 52672);
  float* bobias = (float*)(W + 55744);
  float* counts = (float*)(W + 59840);        // 393216 B
  int*   deg    = (int*)(W + 453056);
  int*   offs   = (int*)(W + 518592);
  int*   cursor = (int*)(W + 584192);
  int*   elist  = (int*)(W + 649728);
  unsigned short* BTcat = (unsigned short*)(W + 1698304);   // 5898240 B
  unsigned short* yb0   = (unsigned short*)(W + 7596544);   // [N][D] bf16
  unsigned short* Y23   = (unsigned short*)(W + 32762368);  // [N][1536] bf16
  unsigned short* yb1   = (unsigned short*)(W + 83094016);  // [N][D] bf16
  const size_t NEED_B = 108259840;
  if (ws_size < NEED_B) {
    k_fill<<<(int)(((long)out_size + 255) / 256), 256, 0, stream>>>(
        out, (long)out_size, (float)(ws_size >> 20) * 100.0f);
    return;
  }

  // ---- d_out scratch map (64 MB) ----
  unsigned short* h16   = (unsigned short*)d_out;
  unsigned short* wt_in = (unsigned short*)d_out + 29360128;
  unsigned short* Y01   = (unsigned short*)d_out;
  float* hf = out;
  unsigned short* wt_out = BTcat;

  // 0. dtype detect + batched param conversion
  k_detect<<<1, 256, 0, stream>>>((const unsigned short*)h_text, flags);
  {
    dim3 g(6, 8);
    k_cvt8<<<g, 256, 0, stream>>>(b_in, comp, convb, bn_g, bn_b, b_out, ln_g,
                                  ln_b, fpar, flags);
  }

  // 0b. h16 = bf16(h_text); wt_in = w_in^T
  k_cvtb<<<(NN * HIDD) / 256, 256, 0, stream>>>(h_text, h16, NN * HIDD, flags);
  {
    dim3 g(DD / 64, HIDD / 64);
    k_transpose<<<g, 256, 0, stream>>>(w_in, 0, wt_in, HIDD, DD, HIDD, 0,
                                       nullptr, flags);
  }

  // 1. yb0(bf16) = relu(h16 @ w_in + b_in)
  k_mgemm<1, 1, 1><<<(DD / 128) * (NN / 128), 256, 0, stream>>>(
      h16, wt_in, f_bin, yb0, NN, DD, HIDD);

  // 2. counts + CSR by dst; affA = identity; zero rbias + stats
  hipMemsetAsync(counts, 0, (size_t)RR * NN * sizeof(float), stream);
  k_count<<<NE / 256, 256, 0, stream>>>(etype, dst, counts);
  hipMemsetAsync(deg, 0, NN * sizeof(int), stream);
  k_deg<<<NE / 256, 256, 0, stream>>>(dst, deg);
  k_scan<<<1, 256, 0, stream>>>(deg, offs, cursor);
  k_place<<<NE / 256, 256, 0, stream>>>(src, dst, etype, cursor, elist);
  k_affinit<<<8, 256, 0, stream>>>(affA_g, affA_d, rbias, stats);

  // 3. RGCN layers (BN folded into consumers via affine)
  for (int l = 0; l < LL; ++l) {
    const long boff = (long)l * BB * DD * DD;
    const long roff = (long)l * DD * DD;
    const float* compL = f_comp + l * RR * BB;
    const float* cbL   = f_cb + l * DD;
    const float* gL    = f_bng + l * DD;
    const float* bL    = f_bnb + l * DD;
    const float* aff_g = (l == 0) ? affA_g : affB_g;
    const float* aff_d = (l == 0) ? affA_d : affB_d;
    float* affo_g = (l == 0) ? affB_g : affA_g;
    float* affo_d = (l == 0) ? affB_d : affA_d;
    const unsigned short* ybin = (l == 0) ? yb0 : yb1;
    unsigned short* ybout      = (l == 0) ? yb1 : yb0;

    // rbias += conv_bias + delta^T root[l]  (rbias pre-zeroed)
    {
      dim3 g(DD / 256, 16);
      k_rowbias<<<g, 256, 0, stream>>>(root, roff, DD, aff_d, cbL, rbias, flags);
    }
    // BTcat = [grho*root | B0..B3]^T
    {
      dim3 g(DD / 64, DD / 64, 5);
      k_tbatch<<<g, 256, 0, stream>>>(root, roff, basis, boff, aff_g, BTcat, flags);
    }
    // gather on raw yb, affine at write
    k_gather4<<<NN, 192, 0, stream>>>(offs, elist, counts, compL, aff_g, aff_d,
                                      ybin, Y01, Y23);
    // fused GEMM + epilogue (BM=128 x BN=192; stats pre-zeroed)
    k_mgemm3<<<(DD / 192) * (NN / 128), 256, 0, stream>>>(
        ybin, Y01, Y23, BTcat, rbias, aff_g, aff_d, ybout, stats, stats + DD);
    // next affine from BN stats; re-zero stats; zero next bias target
    k_aff<<<4, 256, 0, stream>>>(stats, stats + DD, gL, bL, affo_g, affo_d,
                                 (l == 0) ? rbias : bobias,
                                 (l == 0) ? DD : HIDD);
  }

  // 4. out-proj with BN folded (bobias zeroed by layer-1 k_aff)
  {
    dim3 g(HIDD / 256, 16);
    k_rowbias<<<g, 256, 0, stream>>>(w_out, 0, HIDD, affA_d, f_bout, bobias, flags);
  }
  {
    dim3 g(HIDD / 64, DD / 64);
    k_transpose<<<g, 256, 0, stream>>>(w_out, 0, wt_out, DD, HIDD, DD, 0,
                                       affA_g, flags);
  }
  k_mgemm<1, 0, 0><<<(HIDD / 128) * (NN / 128), 256, 0, stream>>>(
      yb0, wt_out, bobias, hf, NN, HIDD, DD);

  // 5. LayerNorm in-place in d_out (f32 -> f32)
  k_layernorm<<<NN, 256, 0, stream>>>(hf, f_lng, f_lnb, out);
}

// Round 21
// 715.310 us; speedup vs baseline: 1.1316x; 1.1316x over previous
//
#include <hip/hip_runtime.h>
#include <hip/hip_bf16.h>

#define NN 16384      // nodes
#define NE 262144     // edges
#define HIDD 1024
#define DD 768
#define RR 6
#define BB 4
#define LL 2
#define BN_EPS 1e-5f
#define LN_EPS 1e-5f

typedef __attribute__((ext_vector_type(8))) short bf16x8;
typedef __attribute__((ext_vector_type(4))) float f32x4;

__device__ __forceinline__ float b2f(unsigned short u) {
  union { unsigned int i; float f; } c;
  c.i = ((unsigned int)u) << 16;
  return c.f;
}
__device__ __forceinline__ unsigned short f2b(float f) {  // RNE
  union { float f; unsigned int u; } c;
  c.f = f;
  unsigned int x = c.u;
  x += 0x7FFFu + ((x >> 16) & 1u);
  return (unsigned short)(x >> 16);
}

__device__ __forceinline__ void gll16(const unsigned short* g, unsigned short* l) {
  __builtin_amdgcn_global_load_lds(
      (const __attribute__((address_space(1))) unsigned int*)g,
      (__attribute__((address_space(3))) unsigned int*)l, 16, 0, 0);
}

// dtype detector: flag=1 -> inputs f32, flag=0 -> inputs bf16.
__global__ void k_detect(const unsigned short* __restrict__ h, int* __restrict__ flag) {
  __shared__ int sh[256];
  int cnt = 0;
  for (int k = 0; k < 256; ++k) {
    ushort4 t = *(const ushort4*)&h[(size_t)(k * 256 + threadIdx.x) * 4];
    if ((t.x & 0x7F80) == 0x7F80) cnt++;
    if ((t.y & 0x7F80) == 0x7F80) cnt++;
    if ((t.z & 0x7F80) == 0x7F80) cnt++;
    if ((t.w & 0x7F80) == 0x7F80) cnt++;
  }
  sh[threadIdx.x] = cnt;
  __syncthreads();
  if (threadIdx.x == 0) {
    int t = 0;
    for (int i = 0; i < 256; ++i) t += sh[i];
    flag[0] = (t > 16) ? 1 : 0;
  }
}

// MODE: 0 = raw input (flag-dependent), 1 = f32, 2 = bf16
template <int MODE>
__device__ __forceinline__ float load1t(const void* p, size_t i, int isf32) {
  if (MODE == 1 || (MODE == 0 && isf32)) return ((const float*)p)[i];
  return b2f(((const unsigned short*)p)[i]);
}

// batched param conversion: 8 segments -> fpar
__global__ void k_cvt8(const void* s0, const void* s1, const void* s2, const void* s3,
                       const void* s4, const void* s5, const void* s6, const void* s7,
                       float* __restrict__ fpar, const int* __restrict__ flagp) {
  const int isf32 = flagp[0];
  const int seg = blockIdx.y;
  const int lens[8] = {768, 48, 1536, 1536, 1536, 1024, 1024, 1024};
  const int offs_[8] = {0, 768, 816, 2352, 3888, 5424, 6448, 7472};
  const void* srcs[8] = {s0, s1, s2, s3, s4, s5, s6, s7};
  int i = blockIdx.x * 256 + threadIdx.x;
  if (i < lens[seg]) fpar[offs_[seg] + i] = load1t<0>(srcs[seg], i, isf32);
}

// raw input -> bf16 copy
__global__ void k_cvtb(const void* __restrict__ in, unsigned short* __restrict__ out,
                       int n, const int* __restrict__ flagp) {
  const int isf32 = flagp[0];
  int i = blockIdx.x * 256 + threadIdx.x;
  if (i < n) out[i] = f2b(load1t<0>(in, (size_t)i, isf32));
}

// diagnostic fill (f32 out)
__global__ void k_fill(float* __restrict__ out, long n, float val) {
  long i = (long)blockIdx.x * 256 + threadIdx.x;
  if (i < n) out[i] = val;
}

// LDS-tiled transpose: src [I][J] -> dst[j*dstStride + dstOff + i] bf16.
// Optional per-row scale (rowsc[i]) applied at load; rowsc==nullptr -> 1.
__global__ __launch_bounds__(256) void k_transpose(const void* __restrict__ src,
                                                   long ioff,
                                                   unsigned short* __restrict__ dst,
                                                   int I, int J, int dstStride,
                                                   int dstOff,
                                                   const float* __restrict__ rowsc,
                                                   const int* __restrict__ flagp) {
  const int isf32 = flagp[0];
  __shared__ unsigned short t[64][65];
  const int j0 = blockIdx.x * 64, i0 = blockIdx.y * 64;
  const int tx = threadIdx.x & 63, ty = threadIdx.x >> 6;
  for (int rr = ty; rr < 64; rr += 4) {
    float sc = rowsc ? rowsc[i0 + rr] : 1.0f;
    t[rr][tx] = f2b(sc * load1t<0>(src, (size_t)ioff + (size_t)(i0 + rr) * J + j0 + tx, isf32));
  }
  __syncthreads();
  for (int rr = ty; rr < 64; rr += 4)
    dst[(size_t)(j0 + rr) * dstStride + dstOff + i0 + tx] = t[tx][rr];
}

// batched: BTcat[n][z*768 + k] = W_z[k][n]; z=0 root (rows scaled by grho[k]),
// z=1..4 basis[z-1] (unscaled)
__global__ __launch_bounds__(256) void k_tbatch(const void* __restrict__ root, long roff,
                                                const void* __restrict__ basis, long boff,
                                                const float* __restrict__ grho,
                                                unsigned short* __restrict__ BT,
                                                const int* __restrict__ flagp) {
  const int isf32 = flagp[0];
  const int z = blockIdx.z;
  const void* src = (z == 0) ? root : basis;
  const long off = (z == 0) ? roff : boff + (long)(z - 1) * DD * DD;
  __shared__ unsigned short t[64][65];
  const int j0 = blockIdx.x * 64, i0 = blockIdx.y * 64;
  const int tx = threadIdx.x & 63, ty = threadIdx.x >> 6;
  for (int rr = ty; rr < 64; rr += 4) {
    float sc = (z == 0) ? grho[i0 + rr] : 1.0f;
    t[rr][tx] = f2b(sc * load1t<0>(src, (size_t)off + (size_t)(i0 + rr) * DD + j0 + tx, isf32));
  }
  __syncthreads();
  for (int rr = ty; rr < 64; rr += 4)
    BT[(size_t)(j0 + rr) * (5 * DD) + z * DD + i0 + tx] = t[tx][rr];
}

// affine init: grho=1, dlt=0; zero rbias + stats. grid 8x256.
__global__ void k_affinit(float* __restrict__ grho, float* __restrict__ dlt,
                          float* __restrict__ rbias, float* __restrict__ stats) {
  int i = blockIdx.x * 256 + threadIdx.x;
  if (i < DD) { grho[i] = 1.0f; dlt[i] = 0.0f; rbias[i] = 0.0f; }
  if (i < 2 * DD) stats[i] = 0.0f;
}

// affine from BN stats; also re-zero stats and zero zbuf[0..zn). grid 4x256.
__global__ void k_aff(float* __restrict__ sums, float* __restrict__ sqs,
                      const float* __restrict__ gamma, const float* __restrict__ beta,
                      float* __restrict__ grho, float* __restrict__ dlt,
                      float* __restrict__ zbuf, int zn) {
  int c = blockIdx.x * 256 + threadIdx.x;
  if (c < DD) {
    float mu = sums[c] * (1.0f / NN);
    float var = sqs[c] * (1.0f / NN) - mu * mu;
    float gr = gamma[c] * rsqrtf(var + BN_EPS);
    grho[c] = gr;
    dlt[c] = beta[c] - gr * mu;
    sums[c] = 0.0f;
    sqs[c] = 0.0f;
  }
  if (c < zn) zbuf[c] = 0.0f;
}

// outb[n] += base[n](chunk0) + sum_{k in chunk} delta[k]*mat[ioff+k*J+n]
// grid = (J/256, 16 k-chunks of 48). outb must be zeroed.
__global__ void k_rowbias(const void* __restrict__ mat, long ioff, int J,
                          const float* __restrict__ delta,
                          const float* __restrict__ base,
                          float* __restrict__ outb,
                          const int* __restrict__ flagp) {
  const int isf32 = flagp[0];
  const int n = blockIdx.x * 256 + threadIdx.x;
  if (n >= J) return;
  const int kc = blockIdx.y;
  float s = (kc == 0 && base) ? base[n] : 0.0f;
  const int k0 = kc * 48;
#pragma unroll 4
  for (int k = k0; k < k0 + 48; ++k)
    s += delta[k] * load1t<0>(mat, (size_t)ioff + (size_t)k * J + n, isf32);
  atomicAdd(&outb[n], s);
}

// ---------------------------------------------------------------------------
// MFMA bf16 GEMM: C[M,N] = A[M,K] @ Bt[N,K]^T (+bias)(relu)
// 128x128 tile, 4 waves, BK=64 (2x32 sub-chunks per barrier pair),
// 16x16x32 MFMA, gll16 staging, XOR bank permutation, bijective XCD swizzle.
// R16/R19-proven structure (empirical optimum of this template).
// ---------------------------------------------------------------------------
template <int BIAS, int RELU, int OUTB>
__global__ __launch_bounds__(256) void k_mgemm(const unsigned short* __restrict__ A,
                                               const unsigned short* __restrict__ Bt,
                                               const float* __restrict__ bias,
                                               void* __restrict__ C,
                                               int M, int Nn, int K) {
  __shared__ __align__(16) unsigned short Alds[2][128 * 32];
  __shared__ __align__(16) unsigned short Blds[2][128 * 32];
  const int tid = threadIdx.x;
  const int lane = tid & 63, w = tid >> 6;
  const int wm = w >> 1, wn = w & 1;
  const int fr = lane & 15, kg = lane >> 4;
  const int nwg = gridDim.x;
  int id = blockIdx.x;
  if ((nwg & 7) == 0) id = (id & 7) * (nwg >> 3) + (id >> 3);
  const int gx = Nn >> 7;
  const int m0 = (id / gx) * 128, n0 = (id % gx) * 128;

  const int srow = w * 16 + (lane >> 2);
  const int sslot = (lane & 3) ^ ((lane >> 3) & 3);
  const unsigned short* ga = A + (size_t)(m0 + srow) * K + sslot * 8;
  const unsigned short* ga2 = ga + (size_t)64 * K;
  const unsigned short* gb = Bt + (size_t)(n0 + srow) * K + sslot * 8;
  const unsigned short* gb2 = gb + (size_t)64 * K;
  const int wo = w * 512;
  const int roff = fr * 32 + ((kg ^ ((fr >> 1) & 3)) * 8);

  f32x4 acc[4][4] = {};

  for (int k0 = 0; k0 < K; k0 += 64) {
    gll16(ga + k0, &Alds[0][wo]);
    gll16(ga2 + k0, &Alds[0][wo + 2048]);
    gll16(gb + k0, &Blds[0][wo]);
    gll16(gb2 + k0, &Blds[0][wo + 2048]);
    gll16(ga + k0 + 32, &Alds[1][wo]);
    gll16(ga2 + k0 + 32, &Alds[1][wo + 2048]);
    gll16(gb + k0 + 32, &Blds[1][wo]);
    gll16(gb2 + k0 + 32, &Blds[1][wo + 2048]);
    __syncthreads();
#pragma unroll
    for (int kh = 0; kh < 2; ++kh) {
      bf16x8 af[4], bfr[4];
#pragma unroll
      for (int i = 0; i < 4; ++i) {
        af[i] = *(const bf16x8*)(&Alds[kh][(wm * 4 + i) * 512 + roff]);
        bfr[i] = *(const bf16x8*)(&Blds[kh][(wn * 4 + i) * 512 + roff]);
      }
#pragma unroll
      for (int i = 0; i < 4; ++i)
#pragma unroll
        for (int j = 0; j < 4; ++j)
          acc[i][j] = __builtin_amdgcn_mfma_f32_16x16x32_bf16(af[i], bfr[j],
                                                              acc[i][j], 0, 0, 0);
    }
    __syncthreads();
  }

  const int orow = (lane >> 4) * 4;
#pragma unroll
  for (int i = 0; i < 4; ++i) {
#pragma unroll
    for (int j = 0; j < 4; ++j) {
      const int n = n0 + wn * 64 + j * 16 + fr;
      const float bv = BIAS ? bias[n] : 0.f;
#pragma unroll
      for (int rg = 0; rg < 4; ++rg) {
        const int m = m0 + wm * 64 + i * 16 + orow + rg;
        const size_t off = (size_t)m * Nn + n;
        float v = acc[i][j][rg] + bv;
        if (RELU) v = fmaxf(v, 0.f);
        if (OUTB) ((unsigned short*)C)[off] = f2b(v);
        else      ((float*)C)[off] = v;
      }
    }
  }
}

// ---------------------------------------------------------------------------
// Fused layer GEMM + epilogue (BN folded), BK=64 (R19-proven):
//   acc = [ybprev|Y01|Y23] @ BTcat^T  (root rows pre-scaled by grho)
//   v = relu(acc + rbias[n]) + (grho[n]*ybprev[m,n] + dlt[n])
//   ybnew = bf16(v); column sums/sumsq via LDS + global atomics
// ---------------------------------------------------------------------------
__global__ __launch_bounds__(256) void k_mgemm3(const unsigned short* __restrict__ ybprev,
                                                const unsigned short* __restrict__ Y01,
                                                const unsigned short* __restrict__ Y23,
                                                const unsigned short* __restrict__ BT,
                                                const float* __restrict__ rbias,
                                                const float* __restrict__ grho,
                                                const float* __restrict__ dlt,
                                                unsigned short* __restrict__ ybnew,
                                                float* __restrict__ sums,
                                                float* __restrict__ sqs) {
  __shared__ __align__(16) unsigned short Alds[2][128 * 32];
  __shared__ __align__(16) unsigned short Blds[2][128 * 32];
  __shared__ float csum[128], csq[128];
  const int tid = threadIdx.x;
  const int lane = tid & 63, w = tid >> 6;
  const int wm = w >> 1, wn = w & 1;
  const int fr = lane & 15, kg = lane >> 4;
  const int nwg = gridDim.x;        // 768
  int id = blockIdx.x;
  id = (id & 7) * (nwg >> 3) + (id >> 3);
  const int m0 = (id / 6) * 128, n0 = (id % 6) * 128;

  const int srow = w * 16 + (lane >> 2);
  const int sslot = (lane & 3) ^ ((lane >> 3) & 3);
  const unsigned short* gxp = ybprev + (size_t)(m0 + srow) * DD + sslot * 8;
  const unsigned short* gxp2 = gxp + (size_t)64 * DD;
  const unsigned short* gy = Y01 + (size_t)(m0 + srow) * 1536 + sslot * 8;
  const unsigned short* gy2 = gy + (size_t)64 * 1536;
  const unsigned short* gz = Y23 + (size_t)(m0 + srow) * 1536 + sslot * 8;
  const unsigned short* gz2 = gz + (size_t)64 * 1536;
  const unsigned short* gb = BT + (size_t)(n0 + srow) * 3840 + sslot * 8;
  const unsigned short* gb2 = gb + (size_t)64 * 3840;
  const int wo = w * 512;
  const int roff = fr * 32 + ((kg ^ ((fr >> 1) & 3)) * 8);

  f32x4 acc[4][4] = {};

  for (int k0 = 0; k0 < 3840; k0 += 64) {
    const unsigned short *pa, *pa2;
    long ko;
    if (k0 < 768)       { pa = gxp; pa2 = gxp2; ko = k0; }
    else if (k0 < 2304) { pa = gy;  pa2 = gy2;  ko = k0 - 768; }
    else                { pa = gz;  pa2 = gz2;  ko = k0 - 2304; }
    gll16(pa + ko, &Alds[0][wo]);
    gll16(pa2 + ko, &Alds[0][wo + 2048]);
    gll16(pa + ko + 32, &Alds[1][wo]);
    gll16(pa2 + ko + 32, &Alds[1][wo + 2048]);
    gll16(gb + k0, &Blds[0][wo]);
    gll16(gb2 + k0, &Blds[0][wo + 2048]);
    gll16(gb + k0 + 32, &Blds[1][wo]);
    gll16(gb2 + k0 + 32, &Blds[1][wo + 2048]);
    __syncthreads();
#pragma unroll
    for (int kh = 0; kh < 2; ++kh) {
      bf16x8 af[4], bfr[4];
#pragma unroll
      for (int i = 0; i < 4; ++i) {
        af[i] = *(const bf16x8*)(&Alds[kh][(wm * 4 + i) * 512 + roff]);
        bfr[i] = *(const bf16x8*)(&Blds[kh][(wn * 4 + i) * 512 + roff]);
      }
#pragma unroll
      for (int i = 0; i < 4; ++i)
#pragma unroll
        for (int j = 0; j < 4; ++j)
          acc[i][j] = __builtin_amdgcn_mfma_f32_16x16x32_bf16(af[i], bfr[j],
                                                              acc[i][j], 0, 0, 0);
    }
    __syncthreads();
  }

  if (tid < 128) { csum[tid] = 0.f; csq[tid] = 0.f; }
  __syncthreads();
  const int orow = (lane >> 4) * 4;
#pragma unroll
  for (int j = 0; j < 4; ++j) {
    const int nloc = wn * 64 + j * 16 + fr;
    const int n = n0 + nloc;
    const float rb = rbias[n];
    const float gr = grho[n], dl = dlt[n];
    float ps = 0.f, pq = 0.f;
#pragma unroll
    for (int i = 0; i < 4; ++i) {
#pragma unroll
      for (int rg = 0; rg < 4; ++rg) {
        const int m = m0 + wm * 64 + i * 16 + orow + rg;
        float xin = gr * b2f(ybprev[(size_t)m * DD + n]) + dl;
        float v = fmaxf(acc[i][j][rg] + rb, 0.f) + xin;
        ybnew[(size_t)m * DD + n] = f2b(v);
        ps += v;
        pq += v * v;
      }
    }
    atomicAdd(&csum[nloc], ps);
    atomicAdd(&csq[nloc], pq);
  }
  __syncthreads();
  if (tid < 128) {
    atomicAdd(&sums[n0 + tid], csum[tid]);
    atomicAdd(&sqs[n0 + tid], csq[tid]);
  }
}

// counts[r,dst] += 1
__global__ void k_count(const int* __restrict__ et, const int* __restrict__ dst,
                        float* __restrict__ counts) {
  int e = blockIdx.x * 256 + threadIdx.x;
  if (e < NE) atomicAdd(&counts[(size_t)et[e] * NN + dst[e]], 1.0f);
}

// ---- CSR build (by dst) -----------------------------------------------------
__global__ void k_deg(const int* __restrict__ dst, int* __restrict__ deg) {
  int e = blockIdx.x * 256 + threadIdx.x;
  if (e < NE) atomicAdd(&deg[dst[e]], 1);
}

__global__ __launch_bounds__(256) void k_scan(const int* __restrict__ deg,
                                              int* __restrict__ offs,
                                              int* __restrict__ cursor) {
  __shared__ int part[256];
  const int base = threadIdx.x * 64;
  int s = 0;
  for (int i = 0; i < 64; ++i) s += deg[base + i];
  part[threadIdx.x] = s;
  __syncthreads();
  if (threadIdx.x == 0) {
    int run = 0;
    for (int i = 0; i < 256; ++i) { int t = part[i]; part[i] = run; run += t; }
  }
  __syncthreads();
  int run = part[threadIdx.x];
  for (int i = 0; i < 64; ++i) {
    offs[base + i] = run;
    cursor[base + i] = run;
    run += deg[base + i];
  }
  if (threadIdx.x == 255) offs[NN] = run;
}

// elist[slot] = src | (et<<20)
__global__ void k_place(const int* __restrict__ src, const int* __restrict__ dst,
                        const int* __restrict__ et, int* __restrict__ cursor,
                        int* __restrict__ elist) {
  int e = blockIdx.x * 256 + threadIdx.x;
  if (e >= NE) return;
  int d = dst[e];
  int slot = atomicAdd(&cursor[d], 1);
  elist[slot] = src[e] | (et[e] << 20);
}

// ---- single-pass gather on raw yb, BN affine applied at write, 8-edge ILP
__global__ __launch_bounds__(192) void k_gather4(const int* __restrict__ offs,
                                                 const int* __restrict__ elist,
                                                 const float* __restrict__ counts,
                                                 const float* __restrict__ compL,
                                                 const float* __restrict__ grho,
                                                 const float* __restrict__ dlt,
                                                 const unsigned short* __restrict__ yb,
                                                 unsigned short* __restrict__ Y01,
                                                 unsigned short* __restrict__ Y23) {
  const int d = blockIdx.x;
  const int tid = threadIdx.x;
  __shared__ float sw[RR][4];
  if (tid < 4 * RR) {
    const int r = tid >> 2, j = tid & 3;
    const float c = counts[(size_t)r * NN + d];
    sw[r][j] = (c > 0.f) ? compL[r * BB + j] / c : 0.f;
  }
  __syncthreads();
  const int beg = offs[d], end = offs[d + 1];
  float a0[4] = {}, a1[4] = {}, a2[4] = {}, a3[4] = {};
  float ws0 = 0.f, ws1 = 0.f, ws2 = 0.f, ws3 = 0.f;
  int e = beg;
  for (; e + 7 < end; e += 8) {
    int v[8];
#pragma unroll
    for (int q = 0; q < 8; ++q) v[q] = elist[e + q];
    ushort4 t[8];
#pragma unroll
    for (int q = 0; q < 8; ++q)
      t[q] = *(const ushort4*)&yb[(size_t)(v[q] & 0xFFFFF) * DD + tid * 4];
#pragma unroll
    for (int q = 0; q < 8; ++q) {
      const int r = v[q] >> 20;
      const float w0 = sw[r][0], w1 = sw[r][1], w2 = sw[r][2], w3 = sw[r][3];
      ws0 += w0; ws1 += w1; ws2 += w2; ws3 += w3;
      const float f[4] = {b2f(t[q].x), b2f(t[q].y), b2f(t[q].z), b2f(t[q].w)};
#pragma unroll
      for (int c = 0; c < 4; ++c) {
        a0[c] += w0 * f[c];
        a1[c] += w1 * f[c];
        a2[c] += w2 * f[c];
        a3[c] += w3 * f[c];
      }
    }
  }
  for (; e < end; ++e) {
    const int v = elist[e];
    const int s = v & 0xFFFFF, r = v >> 20;
    ushort4 t = *(const ushort4*)&yb[(size_t)s * DD + tid * 4];
    const float w0 = sw[r][0], w1 = sw[r][1], w2 = sw[r][2], w3 = sw[r][3];
    ws0 += w0; ws1 += w1; ws2 += w2; ws3 += w3;
    const float f[4] = {b2f(t.x), b2f(t.y), b2f(t.z), b2f(t.w)};
#pragma unroll
    for (int c = 0; c < 4; ++c) {
      a0[c] += w0 * f[c];
      a1[c] += w1 * f[c];
      a2[c] += w2 * f[c];
      a3[c] += w3 * f[c];
    }
  }
  const float4 gr = *(const float4*)&grho[tid * 4];
  const float4 dl = *(const float4*)&dlt[tid * 4];
  const float grv[4] = {gr.x, gr.y, gr.z, gr.w};
  const float dlv[4] = {dl.x, dl.y, dl.z, dl.w};
  ushort4 o;
  o.x = f2b(grv[0] * a0[0] + dlv[0] * ws0);
  o.y = f2b(grv[1] * a0[1] + dlv[1] * ws0);
  o.z = f2b(grv[2] * a0[2] + dlv[2] * ws0);
  o.w = f2b(grv[3] * a0[3] + dlv[3] * ws0);
  *(ushort4*)&Y01[(size_t)d * 1536 + tid * 4] = o;
  o.x = f2b(grv[0] * a1[0] + dlv[0] * ws1);
  o.y = f2b(grv[1] * a1[1] + dlv[1] * ws1);
  o.z = f2b(grv[2] * a1[2] + dlv[2] * ws1);
  o.w = f2b(grv[3] * a1[3] + dlv[3] * ws1);
  *(ushort4*)&Y01[(size_t)d * 1536 + DD + tid * 4] = o;
  o.x = f2b(grv[0] * a2[0] + dlv[0] * ws2);
  o.y = f2b(grv[1] * a2[1] + dlv[1] * ws2);
  o.z = f2b(grv[2] * a2[2] + dlv[2] * ws2);
  o.w = f2b(grv[3] * a2[3] + dlv[3] * ws2);
  *(ushort4*)&Y23[(size_t)d * 1536 + tid * 4] = o;
  o.x = f2b(grv[0] * a3[0] + dlv[0] * ws3);
  o.y = f2b(grv[1] * a3[1] + dlv[1] * ws3);
  o.z = f2b(grv[2] * a3[2] + dlv[2] * ws3);
  o.w = f2b(grv[3] * a3[3] + dlv[3] * ws3);
  *(ushort4*)&Y23[(size_t)d * 1536 + DD + tid * 4] = o;
}

// row LayerNorm over HID=1024, f32 in/out, in-place safe
__global__ __launch_bounds__(256) void k_layernorm(const float* __restrict__ hf,
                                                   const float* __restrict__ gamma,
                                                   const float* __restrict__ beta,
                                                   float* __restrict__ out) {
  const int row = blockIdx.x;
  const float* h = hf + (size_t)row * HIDD;
  float v[4];
  float s = 0.f, sq = 0.f;
#pragma unroll
  for (int j = 0; j < 4; ++j) {
    v[j] = h[threadIdx.x + j * 256];
    s += v[j];
    sq += v[j] * v[j];
  }
#pragma unroll
  for (int off = 32; off > 0; off >>= 1) {
    s += __shfl_down(s, off);
    sq += __shfl_down(sq, off);
  }
  __shared__ float ps[4], pq[4];
  const int lane = threadIdx.x & 63, wv = threadIdx.x >> 6;
  if (lane == 0) { ps[wv] = s; pq[wv] = sq; }
  __syncthreads();
  if (threadIdx.x == 0) {
    float ts = ps[0] + ps[1] + ps[2] + ps[3];
    float tq = pq[0] + pq[1] + pq[2] + pq[3];
    float mu = ts * (1.0f / HIDD);
    float var = tq * (1.0f / HIDD) - mu * mu;
    ps[0] = mu;
    pq[0] = rsqrtf(var + LN_EPS);
  }
  __syncthreads();
  const float mu = ps[0], rstd = pq[0];
#pragma unroll
  for (int j = 0; j < 4; ++j) {
    const int c = threadIdx.x + j * 256;
    out[(size_t)row * HIDD + c] = gamma[c] * (v[j] - mu) * rstd + beta[c];
  }
}

extern "C" void kernel_launch(void* const* d_in, const int* in_sizes, int n_in,
                              void* d_out, int out_size, void* d_ws, size_t ws_size,
                              hipStream_t stream) {
  const void* h_text = d_in[0];
  const int* ei      = (const int*)d_in[1];
  const int* etype   = (const int*)d_in[2];
  const void* w_in  = d_in[3];
  const void* b_in  = d_in[4];
  const void* basis = d_in[5];
  const void* comp  = d_in[6];
  const void* root  = d_in[7];
  const void* convb = d_in[8];
  const void* bn_g  = d_in[9];
  const void* bn_b  = d_in[10];
  const void* w_out = d_in[11];
  const void* b_out = d_in[12];
  const void* ln_g  = d_in[13];
  const void* ln_b  = d_in[14];
  float* out = (float*)d_out;      // output is f32

  const int* src = ei;
  const int* dst = ei + NE;

  // ---- ws layout (byte offsets, 64B-aligned). Total ~108.3 MB.
  char* W = (char*)d_ws;
  int*   flags  = (int*)(W + 0);              // 256 B
  float* stats  = (float*)(W + 256);          // 6144 B
  float* fpar   = (float*)(W + 6400);         // 33984 B
  float* f_bin  = fpar;
  float* f_comp = fpar + 768;
  float* f_cb   = fpar + 816;
  float* f_bng  = fpar + 2352;
  float* f_bnb  = fpar + 3888;
  float* f_bout = fpar + 5424;
  float* f_lng  = fpar + 6448;
  float* f_lnb  = fpar + 7472;
  float* affA_g = (float*)(W + 40384);
  float* affA_d = affA_g + DD;
  float* affB_g = (float*)(W + 46528);
  float* affB_d = affB_g + DD;
  float* rbias  = (float*)(W + 52672);
  float* bobias = (float*)(W + 55744);
  float* counts = (float*)(W + 59840);        // 393216 B
  int*   deg    = (int*)(W + 453056);
  int*   offs   = (int*)(W + 518592);
  int*   cursor = (int*)(W + 584192);
  int*   elist  = (int*)(W + 649728);
  unsigned short* BTcat = (unsigned short*)(W + 1698304);   // 5898240 B
  unsigned short* yb0   = (unsigned short*)(W + 7596544);   // [N][D] bf16
  unsigned short* Y23   = (unsigned short*)(W + 32762368);  // [N][1536] bf16
  unsigned short* yb1   = (unsigned short*)(W + 83094016);  // [N][D] bf16
  const size_t NEED_B = 108259840;
  if (ws_size < NEED_B) {
    k_fill<<<(int)(((long)out_size + 255) / 256), 256, 0, stream>>>(
        out, (long)out_size, (float)(ws_size >> 20) * 100.0f);
    return;
  }

  // ---- d_out scratch map (64 MB) ----
  unsigned short* h16   = (unsigned short*)d_out;
  unsigned short* wt_in = (unsigned short*)d_out + 29360128;
  unsigned short* Y01   = (unsigned short*)d_out;
  float* hf = out;
  unsigned short* wt_out = BTcat;

  // 0. dtype detect + batched param conversion
  k_detect<<<1, 256, 0, stream>>>((const unsigned short*)h_text, flags);
  {
    dim3 g(6, 8);
    k_cvt8<<<g, 256, 0, stream>>>(b_in, comp, convb, bn_g, bn_b, b_out, ln_g,
                                  ln_b, fpar, flags);
  }

  // 0b. h16 = bf16(h_text); wt_in = w_in^T
  k_cvtb<<<(NN * HIDD) / 256, 256, 0, stream>>>(h_text, h16, NN * HIDD, flags);
  {
    dim3 g(DD / 64, HIDD / 64);
    k_transpose<<<g, 256, 0, stream>>>(w_in, 0, wt_in, HIDD, DD, HIDD, 0,
                                       nullptr, flags);
  }

  // 1. yb0(bf16) = relu(h16 @ w_in + b_in)
  k_mgemm<1, 1, 1><<<(DD / 128) * (NN / 128), 256, 0, stream>>>(
      h16, wt_in, f_bin, yb0, NN, DD, HIDD);

  // 2. counts + CSR by dst; affA = identity; zero rbias + stats
  hipMemsetAsync(counts, 0, (size_t)RR * NN * sizeof(float), stream);
  k_count<<<NE / 256, 256, 0, stream>>>(etype, dst, counts);
  hipMemsetAsync(deg, 0, NN * sizeof(int), stream);
  k_deg<<<NE / 256, 256, 0, stream>>>(dst, deg);
  k_scan<<<1, 256, 0, stream>>>(deg, offs, cursor);
  k_place<<<NE / 256, 256, 0, stream>>>(src, dst, etype, cursor, elist);
  k_affinit<<<8, 256, 0, stream>>>(affA_g, affA_d, rbias, stats);

  // 3. RGCN layers (BN folded into consumers via affine)
  for (int l = 0; l < LL; ++l) {
    const long boff = (long)l * BB * DD * DD;
    const long roff = (long)l * DD * DD;
    const float* compL = f_comp + l * RR * BB;
    const float* cbL   = f_cb + l * DD;
    const float* gL    = f_bng + l * DD;
    const float* bL    = f_bnb + l * DD;
    const float* aff_g = (l == 0) ? affA_g : affB_g;
    const float* aff_d = (l == 0) ? affA_d : affB_d;
    float* affo_g = (l == 0) ? affB_g : affA_g;
    float* affo_d = (l == 0) ? affB_d : affA_d;
    const unsigned short* ybin = (l == 0) ? yb0 : yb1;
    unsigned short* ybout      = (l == 0) ? yb1 : yb0;

    // rbias += conv_bias + delta^T root[l]  (rbias pre-zeroed)
    {
      dim3 g(DD / 256, 16);
      k_rowbias<<<g, 256, 0, stream>>>(root, roff, DD, aff_d, cbL, rbias, flags);
    }
    // BTcat = [grho*root | B0..B3]^T
    {
      dim3 g(DD / 64, DD / 64, 5);
      k_tbatch<<<g, 256, 0, stream>>>(root, roff, basis, boff, aff_g, BTcat, flags);
    }
    // gather on raw yb, affine at write
    k_gather4<<<NN, 192, 0, stream>>>(offs, elist, counts, compL, aff_g, aff_d,
                                      ybin, Y01, Y23);
    // fused GEMM + epilogue (stats pre-zeroed)
    k_mgemm3<<<(DD / 128) * (NN / 128), 256, 0, stream>>>(
        ybin, Y01, Y23, BTcat, rbias, aff_g, aff_d, ybout, stats, stats + DD);
    // next affine from BN stats; re-zero stats; zero next bias target
    k_aff<<<4, 256, 0, stream>>>(stats, stats + DD, gL, bL, affo_g, affo_d,
                                 (l == 0) ? rbias : bobias,
                                 (l == 0) ? DD : HIDD);
  }

  // 4. out-proj with BN folded (bobias zeroed by layer-1 k_aff)
  {
    dim3 g(HIDD / 256, 16);
    k_rowbias<<<g, 256, 0, stream>>>(w_out, 0, HIDD, affA_d, f_bout, bobias, flags);
  }
  {
    dim3 g(HIDD / 64, DD / 64);
    k_transpose<<<g, 256, 0, stream>>>(w_out, 0, wt_out, DD, HIDD, DD, 0,
                                       affA_g, flags);
  }
  k_mgemm<1, 0, 0><<<(HIDD / 128) * (NN / 128), 256, 0, stream>>>(
      yb0, wt_out, bobias, hf, NN, HIDD, DD);

  // 5. LayerNorm in-place in d_out (f32 -> f32)
  k_layernorm<<<NN, 256, 0, stream>>>(hf, f_lng, f_lnb, out);
}